// Round 9
// baseline (59.871 us; speedup 1.0000x reference)
//
#include <hip/hip_runtime.h>
#include <cmath>
#include <cstdint>
#include <cstddef>

using u32 = unsigned int;
typedef float f32x4 __attribute__((ext_vector_type(4)));

// plain (cacheable) vector store — out working set fits LLC; dirty lines stay
// resident across graph replays, so avoid nontemporal/no-allocate hints.
__device__ inline void st4(float* p, float a, float b, float c, float d)
{
    f32x4 v; v.x = a; v.y = b; v.z = c; v.w = d;
    *(f32x4*)p = v;
}

// ---------------- compile-time geometry ----------------
// levels n = [4,4,5,6,8,10,12,14,17,21,25,30,36,44,53,63/64]
// kh = 64//n = [16,16,12,10,8,6,5,4,3,3,2,2,1,1,1,1]
// grid res nh = 64//kh (levels 0..11; levels 12..15 are identity, nh=64)
constexpr int NH[12] = {4,4,5,6,8,10,12,16,21,21,32,32};

// float offsets of max-pool grids in ws  (layout [b][c][p(h)][w][d])
constexpr int OFF_M2  = 0;        // 32^3 *12 = 393216
constexpr int OFF_M3  = 393216;   // 21^3 *12 = 111132
constexpr int OFF_M5  = 504348;   // 12^3 *12 = 20736
constexpr int OFF_M4  = 525084;   // 16^3 *12 = 49152
constexpr int OFF_M6  = 574236;   // 10^3 *12 = 12000
constexpr int OFF_M8  = 586236;   //  8^3 *12 = 6144
constexpr int OFF_M10 = 592380;   //  6^3 *12 = 2592
constexpr int OFF_M12 = 594972;   //  5^3 *12 = 1500
constexpr int OFF_M16 = 596472;   //  4^3 *12 = 768  -> end 597240 floats (2.4 MB)

// pool source per interp level
constexpr int POFF[12] = {OFF_M16,OFF_M16,OFF_M12,OFF_M10,OFF_M8,OFF_M6,
                          OFF_M5, OFF_M4, OFF_M3, OFF_M3, OFF_M2, OFF_M2};

constexpr float invf_of(int nh){ return (float)(1.0/(64.0/(double)nh)); }
constexpr float INVF[12] = {invf_of(4),invf_of(4),invf_of(5),invf_of(6),
                            invf_of(8),invf_of(10),invf_of(12),invf_of(16),
                            invf_of(21),invf_of(21),invf_of(32),invf_of(32)};

struct HP { int n[16]; };

__device__ inline float lp(float a, float b, float w){ return fmaf(w, b - a, a); }

// ---------------- K1: ALL max-pools directly from x ----------------
// thread-per-cell: M2 [0,393216), M3 [393216,504348), M5 [504348,525084),
//                  M4 [525084,574236)
// wave-per-cell (tid >= 574464, wid = (tid-574464)/64):
//   M6 wid<12000, M8 <18144, M10 <20736, M12 <22236, M16 <23004
// All windows are exact max over x -> bit-identical to the pyramid version.
__global__ __launch_bounds__(256) void k_pool(const float* __restrict__ x,
                                              float* __restrict__ ws)
{
    int tid = blockIdx.x * 256 + threadIdx.x;
    if (tid < 393216) {                       // M2: 2^3
        int pd = tid & 31, pw = (tid >> 5) & 31, ph = (tid >> 10) & 31;
        int bc = tid >> 15;
        const float* xp = x + (size_t)bc * 262144 + (ph*2)*4096 + (pw*2)*64 + pd*2;
        float2 v00 = *(const float2*)(xp);
        float2 v01 = *(const float2*)(xp + 64);
        float2 v10 = *(const float2*)(xp + 4096);
        float2 v11 = *(const float2*)(xp + 4160);
        float m = fmaxf(fmaxf(fmaxf(v00.x,v00.y), fmaxf(v01.x,v01.y)),
                        fmaxf(fmaxf(v10.x,v10.y), fmaxf(v11.x,v11.y)));
        ws[OFF_M2 + tid] = m;
    } else if (tid < 504348) {                // M3: 3^3
        int idx = tid - 393216;
        int pd = idx % 21; int t2 = idx / 21;
        int pw = t2 % 21;  int t3 = t2 / 21;
        int ph = t3 % 21;  int bc = t3 / 21;
        const float* xp = x + (size_t)bc * 262144 + (ph*3)*4096 + (pw*3)*64 + pd*3;
        float m = -1.f;
        #pragma unroll
        for (int dh = 0; dh < 3; ++dh)
        #pragma unroll
        for (int dw = 0; dw < 3; ++dw) {
            const float* r = xp + dh*4096 + dw*64;
            m = fmaxf(m, fmaxf(fmaxf(r[0], r[1]), r[2]));
        }
        ws[OFF_M3 + idx] = m;
    } else if (tid < 525084) {                // M5: 5^3
        int idx = tid - 504348;
        int pd = idx % 12; int t2 = idx / 12;
        int pw = t2 % 12;  int t3 = t2 / 12;
        int ph = t3 % 12;  int bc = t3 / 12;
        const float* xp = x + (size_t)bc * 262144 + (ph*5)*4096 + (pw*5)*64 + pd*5;
        float m = -1.f;
        #pragma unroll
        for (int dh = 0; dh < 5; ++dh)
        #pragma unroll
        for (int dw = 0; dw < 5; ++dw) {
            const float* r = xp + dh*4096 + dw*64;
            m = fmaxf(m, fmaxf(fmaxf(fmaxf(r[0],r[1]), fmaxf(r[2],r[3])), r[4]));
        }
        ws[OFF_M5 + idx] = m;
    } else if (tid < 574236) {                // M4: 4^3 (float4 rows)
        int idx = tid - 525084;
        int pd = idx & 15, pw = (idx >> 4) & 15, ph = (idx >> 8) & 15, bc = idx >> 12;
        const float* xp = x + (size_t)bc * 262144 + (ph*4)*4096 + (pw*4)*64 + pd*4;
        float m = -1.f;
        #pragma unroll
        for (int dh = 0; dh < 4; ++dh)
        #pragma unroll
        for (int dw = 0; dw < 4; ++dw) {
            float4 v = *(const float4*)(xp + dh*4096 + dw*64);
            m = fmaxf(m, fmaxf(fmaxf(v.x,v.y), fmaxf(v.z,v.w)));
        }
        ws[OFF_M4 + idx] = m;
    } else if (tid >= 574464) {               // wave-per-cell pools
        int wid  = (tid - 574464) >> 6;
        int lane = tid & 63;
        float m = -1.f;
        const float* xp;
        int nrounds, kk2, kk, dst;
        if (wid < 12000) {                    // M6: 6^3 = 216
            int c = wid;
            int pd = c % 10; int t2 = c / 10;
            int pw = t2 % 10; int t3 = t2 / 10;
            int ph = t3 % 10; int bc = t3 / 10;
            xp = x + (size_t)bc * 262144 + (ph*6)*4096 + (pw*6)*64 + pd*6;
            #pragma unroll
            for (int r = 0; r < 4; ++r) {
                int e = lane + (r << 6);
                if (e < 216) {
                    int dh = e / 36, rem = e - dh * 36;
                    int dw = rem / 6, dd = rem - dw * 6;
                    m = fmaxf(m, xp[dh*4096 + dw*64 + dd]);
                }
            }
            dst = OFF_M6 + wid;
        } else if (wid < 18144) {             // M8: 8^3 = 512
            int c = wid - 12000;
            int pd = c & 7, pw = (c >> 3) & 7, ph = (c >> 6) & 7, bc = c >> 9;
            xp = x + (size_t)bc * 262144 + (ph*8)*4096 + (pw*8)*64 + pd*8;
            #pragma unroll
            for (int r = 0; r < 8; ++r) {
                int e = lane + (r << 6);
                int dh = e >> 6, dw = (e >> 3) & 7, dd = e & 7;
                m = fmaxf(m, xp[dh*4096 + dw*64 + dd]);
            }
            dst = OFF_M8 + c;
        } else if (wid < 20736) {             // M10: 10^3 = 1000
            int c = wid - 18144;
            int pd = c % 6; int t2 = c / 6;
            int pw = t2 % 6; int t3 = t2 / 6;
            int ph = t3 % 6; int bc = t3 / 6;
            xp = x + (size_t)bc * 262144 + (ph*10)*4096 + (pw*10)*64 + pd*10;
            #pragma unroll
            for (int r = 0; r < 16; ++r) {
                int e = lane + (r << 6);
                if (e < 1000) {
                    int dh = e / 100, rem = e - dh * 100;
                    int dw = rem / 10, dd = rem - dw * 10;
                    m = fmaxf(m, xp[dh*4096 + dw*64 + dd]);
                }
            }
            dst = OFF_M10 + c;
        } else if (wid < 22236) {             // M12: 12^3 = 1728
            int c = wid - 20736;
            int pd = c % 5; int t2 = c / 5;
            int pw = t2 % 5; int t3 = t2 / 5;
            int ph = t3 % 5; int bc = t3 / 5;
            xp = x + (size_t)bc * 262144 + (ph*12)*4096 + (pw*12)*64 + pd*12;
            #pragma unroll
            for (int r = 0; r < 27; ++r) {
                int e = lane + (r << 6);
                if (e < 1728) {
                    int dh = e / 144, rem = e - dh * 144;
                    int dw = rem / 12, dd = rem - dw * 12;
                    m = fmaxf(m, xp[dh*4096 + dw*64 + dd]);
                }
            }
            dst = OFF_M12 + c;
        } else if (wid < 23004) {             // M16: 16^3 = 4096
            int c = wid - 22236;
            int pd = c & 3, pw = (c >> 2) & 3, ph = (c >> 4) & 3, bc = c >> 6;
            xp = x + (size_t)bc * 262144 + (ph*16)*4096 + (pw*16)*64 + pd*16;
            #pragma unroll
            for (int r = 0; r < 64; ++r) {
                int e = lane + (r << 6);
                int dh = e >> 8, dw = (e >> 4) & 15, dd = e & 15;
                m = fmaxf(m, xp[dh*4096 + dw*64 + dd]);
            }
            dst = OFF_M16 + c;
        } else return;
        #pragma unroll
        for (int s = 32; s; s >>= 1) m = fmaxf(m, __shfl_xor(m, s, 64));
        if (lane == 0) ws[dst] = m;
    }
}

// ---------------- K2: uber output kernel (1-D grid, hand-ordered) ----------
// bid < 512: identity levels 12..15 (heaviest, launch first).
// bid >= 512: interp level lev_order[(bid-512)>>8] = 11,10,...,0 (descending nh),
//             block (b,i) = low 8 bits.
__global__ __launch_bounds__(256) void k_out(const float* __restrict__ x,
                                             const float* __restrict__ ws,
                                             const float* __restrict__ tbl,
                                             float* __restrict__ out, HP hp)
{
    __shared__ float4 shb[3072];
    const int t = threadIdx.x;
    const int bid = blockIdx.x;

    if (bid >= 512) {
        // ---- trilinear interp, separable two-pass ----
        const int e = bid - 512;
        const int l = 11 - (e >> 8);
        const int b = (e >> 6) & 3, i = e & 63;
        float4* plane = shb;                  // [r(pool-d)][q(pool-w)], pitch nh+1
        float*  uf    = (float*)(shb + 1056); // uline [r][ch][64], ch pitch 68, r pitch 204
        const int nh = NH[l];
        const int pitch = nh + 1;
        const float iv = INVF[l];
        const float nf = (float)hp.n[l];

        float fi = (float)i + 0.5f;
        float pp = fminf(fmaxf(fi * iv - 0.5f, 0.f), (float)(nh - 1));
        int p0 = min((int)pp, nh - 2);
        float wp = pp - (float)p0;

        const int nsq = nh * nh, ncb = nsq * nh;
        const float* M   = ws + POFF[l] + (size_t)b * 3 * ncb;   // [c][p][w][d]
        const float* Mp0 = M + p0 * nsq;
        const float* Mp1 = Mp0 + nsq;
        const float* tl  = tbl + (size_t)l * 768;                // level table

        for (int idx = t; idx < nsq; idx += 256) {
            int w = idx / nh, d = idx - w * nh;
            float a0 = Mp0[idx], a1 = Mp0[idx + ncb], a2 = Mp0[idx + 2*ncb];
            u32 h0 = ((u32)(a0*nf) ^ (((u32)(a1*nf))*2654435761u)
                                   ^ (((u32)(a2*nf))*805459861u)) & 255u;
            const float* t0 = tl + h0 * 3;
            float b0 = Mp1[idx], b1 = Mp1[idx + ncb], b2 = Mp1[idx + 2*ncb];
            u32 h1 = ((u32)(b0*nf) ^ (((u32)(b1*nf))*2654435761u)
                                   ^ (((u32)(b2*nf))*805459861u)) & 255u;
            const float* t1 = tl + h1 * 3;
            plane[d * pitch + w] = make_float4(lp(t0[0], t1[0], wp),
                                               lp(t0[1], t1[1], wp),
                                               lp(t0[2], t1[2], wp), 0.f);
        }
        __syncthreads();

        // pass A: q-upsample each plane row to the 64 output-w positions
        for (int e2 = t; e2 < (nh << 6); e2 += 256) {
            int r = e2 >> 6, d = e2 & 63;
            float fk = (float)d + 0.5f;
            float pq = fminf(fmaxf(fk * iv - 0.5f, 0.f), (float)(nh - 1));
            int q0 = min((int)pq, nh - 2);
            float wq = pq - (float)q0;
            const float4* P = plane + r * pitch;
            float4 A = P[q0], B = P[q0 + 1];
            int ub = r * 204 + d;
            uf[ub]       = lp(A.x, B.x, wq);
            uf[ub + 68]  = lp(A.y, B.y, wq);
            uf[ub + 136] = lp(A.z, B.z, wq);
        }
        __syncthreads();

        // pass B: r-lerp + store
        float* op = out + (size_t)b * 12582912 + (size_t)(3 * l) * 262144
                        + (size_t)i * 4096;
        #pragma unroll
        for (int it = 0; it < 4; ++it) {
            int pos = it * 256 + t;           // 0..1023
            int j = pos >> 4, d0 = (pos & 15) << 2;
            float fj = (float)j + 0.5f;
            float pr = fminf(fmaxf(fj * iv - 0.5f, 0.f), (float)(nh - 1));
            int r0 = min((int)pr, nh - 2);
            float wr = pr - (float)r0;
            const float* u0 = uf + r0 * 204 + d0;
            const float* u1 = u0 + 204;
            f32x4 ax = *(const f32x4*)(u0);
            f32x4 ay = *(const f32x4*)(u0 + 68);
            f32x4 az = *(const f32x4*)(u0 + 136);
            f32x4 bx = *(const f32x4*)(u1);
            f32x4 by = *(const f32x4*)(u1 + 68);
            f32x4 bz = *(const f32x4*)(u1 + 136);
            int off = j * 64 + d0;
            st4(op + off,          lp(ax.x,bx.x,wr), lp(ax.y,bx.y,wr),
                                   lp(ax.z,bx.z,wr), lp(ax.w,bx.w,wr));
            st4(op + off + 262144, lp(ay.x,by.x,wr), lp(ay.y,by.y,wr),
                                   lp(ay.z,by.z,wr), lp(ay.w,by.w,wr));
            st4(op + off + 524288, lp(az.x,bz.x,wr), lp(az.y,bz.y,wr),
                                   lp(az.z,bz.z,wr), lp(az.w,bz.w,wr));
        }
    } else {
        // ---- identity levels 12..15, j-half ----
        float4* tab = shb;                    // [1024]
        float*  xs  = (float*)(shb + 1024);   // [3][64][33]
        const int jh = bid & 1;
        const int i  = (bid >> 1) & 63;
        const int b  = (bid >> 7) & 3;

        for (int v = t; v < 1024; v += 256) {
            const float* te = tbl + (size_t)(3072 + v) * 3;   // (12*256+v)*3
            tab[v] = make_float4(te[0], te[1], te[2], 0.f);
        }
        const float* xp = x + (size_t)b * 786432 + (size_t)i * 4096 + jh * 32;
        #pragma unroll
        for (int c = 0; c < 3; ++c)
            for (int k = t; k < 2048; k += 256) {
                int w = k >> 5, jl = k & 31;
                xs[c * 2112 + w * 33 + jl] = xp[(size_t)c * 262144 + w * 64 + jl];
            }
        __syncthreads();

        float nfs[4] = {(float)hp.n[12], (float)hp.n[13],
                        (float)hp.n[14], (float)hp.n[15]};
        float* op = out + (size_t)b * 12582912 + (size_t)36 * 262144
                        + (size_t)i * 4096 + jh * 2048;   // jh*32*64

        #pragma unroll
        for (int it = 0; it < 2; ++it) {
            int pos = it * 256 + t;           // 0..511
            int jl = pos >> 4, d0 = (pos & 15) << 2;
            float xv[3][4];
            #pragma unroll
            for (int dd = 0; dd < 4; ++dd) {
                int wrow = (d0 + dd) * 33 + jl;
                xv[0][dd] = xs[wrow];
                xv[1][dd] = xs[2112 + wrow];
                xv[2][dd] = xs[4224 + wrow];
            }
            #pragma unroll
            for (int u = 0; u < 4; ++u) {
                float4 f[4];
                #pragma unroll
                for (int dd = 0; dd < 4; ++dd) {
                    u32 g0 = (u32)(xv[0][dd] * nfs[u]);
                    u32 g1 = ((u32)(xv[1][dd] * nfs[u])) * 2654435761u;
                    u32 g2 = ((u32)(xv[2][dd] * nfs[u])) * 805459861u;
                    f[dd] = tab[(u << 8) | ((g0 ^ g1 ^ g2) & 255u)];
                }
                int off = u * 786432 + jl * 64 + d0;    // u*3*262144
                st4(op + off,          f[0].x, f[1].x, f[2].x, f[3].x);
                st4(op + off + 262144, f[0].y, f[1].y, f[2].y, f[3].y);
                st4(op + off + 524288, f[0].z, f[1].z, f[2].z, f[3].z);
            }
        }
    }
}

// ---------------- host ----------------
extern "C" void kernel_launch(void* const* d_in, const int* in_sizes, int n_in,
                              void* d_out, int out_size, void* d_ws, size_t ws_size,
                              hipStream_t stream)
{
    const float* x   = (const float*)d_in[0];
    const float* tbl = (const float*)d_in[1];
    float* out = (float*)d_out;
    float* ws  = (float*)d_ws;

    // levels computed with the same libm (exp/log/pow) as the Python reference,
    // so the n=63-vs-64 boundary at l=15 matches bit-for-bit.
    HP hp;
    double growth = std::exp(std::log(16.0) / 15.0);
    for (int l = 0; l < 16; ++l)
        hp.n[l] = (int)std::floor(4.0 * std::pow(growth, (double)l));

    hipLaunchKernelGGL(k_pool, dim3(7995), dim3(256), 0, stream, x, ws);
    hipLaunchKernelGGL(k_out,  dim3(3584), dim3(256), 0, stream, x, ws, tbl, out, hp);
}

// Round 10
// 52.950 us; speedup vs baseline: 1.1307x; 1.1307x over previous
//
#include <hip/hip_runtime.h>
#include <cmath>
#include <cstdint>
#include <cstddef>

using u32 = unsigned int;
typedef float f32x4 __attribute__((ext_vector_type(4)));

__device__ inline void st4(float* p, float a, float b, float c, float d)
{
    f32x4 v; v.x = a; v.y = b; v.z = c; v.w = d;
    *(f32x4*)p = v;
}

// ---------------- compile-time geometry ----------------
// levels n = [4,4,5,6,8,10,12,14,17,21,25,30,36,44,53,63/64]
// kh = 64//n = [16,16,12,10,8,6,5,4,3,3,2,2,1,1,1,1]
// grid res nh = 64//kh (levels 0..11; levels 12..15 are identity, nh=64)
constexpr int NH[12] = {4,4,5,6,8,10,12,16,21,21,32,32};

// float offsets of max-pool grids in ws  (layout [b][c][p(h)][w][d])
constexpr int OFF_M2  = 0;        // 32^3 *12 = 393216
constexpr int OFF_M3  = 393216;   // 21^3 *12 = 111132
constexpr int OFF_M5  = 504348;   // 12^3 *12 = 20736
constexpr int OFF_M4  = 525084;   // 16^3 *12 = 49152
constexpr int OFF_M6  = 574236;   // 10^3 *12 = 12000
constexpr int OFF_M8  = 586236;   //  8^3 *12 = 6144
constexpr int OFF_M10 = 592380;   //  6^3 *12 = 2592
constexpr int OFF_M12 = 594972;   //  5^3 *12 = 1500
constexpr int OFF_M16 = 596472;   //  4^3 *12 = 768  -> end 597240 floats (2.4 MB)

// pool source per interp level
constexpr int POFF[12] = {OFF_M16,OFF_M16,OFF_M12,OFF_M10,OFF_M8,OFF_M6,
                          OFF_M5, OFF_M4, OFF_M3, OFF_M3, OFF_M2, OFF_M2};

constexpr float invf_of(int nh){ return (float)(1.0/(64.0/(double)nh)); }
constexpr float INVF[12] = {invf_of(4),invf_of(4),invf_of(5),invf_of(6),
                            invf_of(8),invf_of(10),invf_of(12),invf_of(16),
                            invf_of(21),invf_of(21),invf_of(32),invf_of(32)};

struct HP { int n[16]; };

__device__ inline float lp(float a, float b, float w){ return fmaf(w, b - a, a); }

// ---------------- K1: base max-pools M2, M3, M5 from x ----------------
__global__ __launch_bounds__(256) void k_pool_base(const float* __restrict__ x,
                                                   float* __restrict__ ws)
{
    int tid = blockIdx.x * 256 + threadIdx.x;
    if (tid < 393216) {                       // M2: 2^3 windows
        int pd = tid & 31, pw = (tid >> 5) & 31, ph = (tid >> 10) & 31;
        int bc = tid >> 15;                   // [0,12)
        const float* xp = x + (size_t)bc * 262144 + (ph*2)*4096 + (pw*2)*64 + pd*2;
        float2 v00 = *(const float2*)(xp);
        float2 v01 = *(const float2*)(xp + 64);
        float2 v10 = *(const float2*)(xp + 4096);
        float2 v11 = *(const float2*)(xp + 4160);
        float m = fmaxf(fmaxf(fmaxf(v00.x,v00.y), fmaxf(v01.x,v01.y)),
                        fmaxf(fmaxf(v10.x,v10.y), fmaxf(v11.x,v11.y)));
        ws[OFF_M2 + tid] = m;
    } else if (tid < 504348) {                // M3: 3^3 windows
        int idx = tid - 393216;
        int pd = idx % 21; int t2 = idx / 21;
        int pw = t2 % 21;  int t3 = t2 / 21;
        int ph = t3 % 21;  int bc = t3 / 21;
        const float* xp = x + (size_t)bc * 262144 + (ph*3)*4096 + (pw*3)*64 + pd*3;
        float m = -1.f;
        #pragma unroll
        for (int dh = 0; dh < 3; ++dh)
        #pragma unroll
        for (int dw = 0; dw < 3; ++dw) {
            const float* r = xp + dh*4096 + dw*64;
            m = fmaxf(m, fmaxf(fmaxf(r[0], r[1]), r[2]));
        }
        ws[OFF_M3 + idx] = m;
    } else if (tid < 525084) {                // M5: 5^3 windows
        int idx = tid - 504348;
        int pd = idx % 12; int t2 = idx / 12;
        int pw = t2 % 12;  int t3 = t2 / 12;
        int ph = t3 % 12;  int bc = t3 / 12;
        const float* xp = x + (size_t)bc * 262144 + (ph*5)*4096 + (pw*5)*64 + pd*5;
        float m = -1.f;
        #pragma unroll
        for (int dh = 0; dh < 5; ++dh)
        #pragma unroll
        for (int dw = 0; dw < 5; ++dw) {
            const float* r = xp + dh*4096 + dw*64;
            m = fmaxf(m, fmaxf(fmaxf(fmaxf(r[0],r[1]), fmaxf(r[2],r[3])), r[4]));
        }
        ws[OFF_M5 + idx] = m;
    }
}

// ---------------- K2: pyramid pools from M2/M3 ----------------
__global__ __launch_bounds__(256) void k_pyr(float* __restrict__ ws)
{
    int tid = blockIdx.x * 256 + threadIdx.x;
    if (tid < 49152) {                        // M16: wave per cell, 8^3 over M2
        int w = tid >> 6, lane = tid & 63;
        int pd = w & 3, pw = (w >> 2) & 3, ph = (w >> 4) & 3, bc = w >> 6;
        const float* m2 = ws + OFF_M2 + (size_t)bc*32768 + (ph*8)*1024 + (pw*8)*32 + pd*8;
        float m = -1.f;
        #pragma unroll
        for (int e = 0; e < 8; ++e) {
            int id2 = (e << 6) | lane;        // 0..511
            int dd = id2 & 7, dw = (id2 >> 3) & 7, dh = id2 >> 6;
            m = fmaxf(m, m2[dh*1024 + dw*32 + dd]);
        }
        #pragma unroll
        for (int s = 32; s; s >>= 1) m = fmaxf(m, __shfl_xor(m, s, 64));
        if (lane == 0) ws[OFF_M16 + w] = m;
    } else if (tid < 98304) {                 // M4: 2^3 over M2
        int idx = tid - 49152;
        int pd = idx & 15, pw = (idx >> 4) & 15, ph = (idx >> 8) & 15, bc = idx >> 12;
        const float* m2 = ws + OFF_M2 + (size_t)bc*32768 + (ph*2)*1024 + (pw*2)*32 + pd*2;
        float2 u0 = *(const float2*)(m2);
        float2 u1 = *(const float2*)(m2 + 32);
        float2 u2 = *(const float2*)(m2 + 1024);
        float2 u3 = *(const float2*)(m2 + 1056);
        ws[OFF_M4 + idx] = fmaxf(fmaxf(fmaxf(u0.x,u0.y), fmaxf(u1.x,u1.y)),
                                 fmaxf(fmaxf(u2.x,u2.y), fmaxf(u3.x,u3.y)));
    } else if (tid < 110304) {                // M6: 3^3 over M2
        int idx = tid - 98304;
        int pd = idx % 10; int t2 = idx / 10;
        int pw = t2 % 10;  int t3 = t2 / 10;
        int ph = t3 % 10;  int bc = t3 / 10;
        const float* m2 = ws + OFF_M2 + (size_t)bc*32768 + (ph*3)*1024 + (pw*3)*32 + pd*3;
        float m = -1.f;
        #pragma unroll
        for (int dh = 0; dh < 3; ++dh)
        #pragma unroll
        for (int dw = 0; dw < 3; ++dw) {
            const float* r = m2 + dh*1024 + dw*32;
            m = fmaxf(m, fmaxf(fmaxf(r[0], r[1]), r[2]));
        }
        ws[OFF_M6 + idx] = m;
    } else if (tid < 116448) {                // M8: 4^3 over M2
        int idx = tid - 110304;
        int pd = idx & 7, pw = (idx >> 3) & 7, ph = (idx >> 6) & 7, bc = idx >> 9;
        const float* m2 = ws + OFF_M2 + (size_t)bc*32768 + (ph*4)*1024 + (pw*4)*32 + pd*4;
        float m = -1.f;
        #pragma unroll
        for (int dh = 0; dh < 4; ++dh)
        #pragma unroll
        for (int dw = 0; dw < 4; ++dw) {
            float4 v = *(const float4*)(m2 + dh*1024 + dw*32);
            m = fmaxf(m, fmaxf(fmaxf(v.x,v.y), fmaxf(v.z,v.w)));
        }
        ws[OFF_M8 + idx] = m;
    } else if (tid < 119040) {                // M10: 5^3 over M2
        int idx = tid - 116448;
        int pd = idx % 6; int t2 = idx / 6;
        int pw = t2 % 6;  int t3 = t2 / 6;
        int ph = t3 % 6;  int bc = t3 / 6;
        const float* m2 = ws + OFF_M2 + (size_t)bc*32768 + (ph*5)*1024 + (pw*5)*32 + pd*5;
        float m = -1.f;
        #pragma unroll
        for (int dh = 0; dh < 5; ++dh)
        #pragma unroll
        for (int dw = 0; dw < 5; ++dw) {
            const float* r = m2 + dh*1024 + dw*32;
            m = fmaxf(m, fmaxf(fmaxf(fmaxf(r[0],r[1]), fmaxf(r[2],r[3])), r[4]));
        }
        ws[OFF_M10 + idx] = m;
    } else if (tid < 120540) {                // M12: 4^3 over M3
        int idx = tid - 119040;
        int pd = idx % 5; int t2 = idx / 5;
        int pw = t2 % 5;  int t3 = t2 / 5;
        int ph = t3 % 5;  int bc = t3 / 5;
        const float* m3 = ws + OFF_M3 + (size_t)bc*9261 + (ph*4)*441 + (pw*4)*21 + pd*4;
        float m = -1.f;
        #pragma unroll
        for (int dh = 0; dh < 4; ++dh)
        #pragma unroll
        for (int dw = 0; dw < 4; ++dw) {
            const float* r = m3 + dh*441 + dw*21;
            m = fmaxf(m, fmaxf(fmaxf(r[0],r[1]), fmaxf(r[2],r[3])));
        }
        ws[OFF_M12 + idx] = m;
    }
}

// ---------------- K3: uber output kernel (LDS <= 36.9 KB -> 4 blocks/CU) ----
// grid (256, 16): y = 0..11 -> interp level y, block x = (b,i)
//                 y = 12..15 -> identity levels 12..15, j-quarter = y-12
// Interp LDS: SoA plane px/py/pz [nh][nh+1] (<=12.7 KB) + uf [r][196] (25.1 KB
//   max) = 36.9 KB. Identity LDS: tab 16.4 KB + xs[3][64][17] 13.1 KB = 29.4 KB.
__global__ __launch_bounds__(256) void k_out(const float* __restrict__ x,
                                             const float* __restrict__ ws,
                                             const float* __restrict__ tbl,
                                             float* __restrict__ out, HP hp)
{
    __shared__ float4 shb4[2360];             // 37760 B
    const int t = threadIdx.x;
    const int l = blockIdx.y;
    const int b = blockIdx.x >> 6, i = blockIdx.x & 63;

    if (l < 12) {
        // ---- trilinear interp level l, separable two-pass ----
        float* px = (float*)shb4;             // [d][w] pitch 33
        float* py = px + 1056;
        float* pz = py + 1056;
        float* uf = pz + 1056;                // [r][{x:0,y:64,z:128}+d] pitch 196
        const int nh = NH[l];
        const float iv = INVF[l];
        const float nf = (float)hp.n[l];

        float fi = (float)i + 0.5f;
        float pp = fminf(fmaxf(fi * iv - 0.5f, 0.f), (float)(nh - 1));
        int p0 = min((int)pp, nh - 2);
        float wp = pp - (float)p0;

        const int nsq = nh * nh, ncb = nsq * nh;
        const float* M   = ws + POFF[l] + (size_t)b * 3 * ncb;   // [c][p][w][d]
        const float* Mp0 = M + p0 * nsq;
        const float* Mp1 = Mp0 + nsq;
        const float* tl  = tbl + (size_t)l * 768;                // level table

        for (int idx = t; idx < nsq; idx += 256) {
            int w = idx / nh, d = idx - w * nh;
            float a0 = Mp0[idx], a1 = Mp0[idx + ncb], a2 = Mp0[idx + 2*ncb];
            u32 h0 = ((u32)(a0*nf) ^ (((u32)(a1*nf))*2654435761u)
                                   ^ (((u32)(a2*nf))*805459861u)) & 255u;
            const float* t0 = tl + h0 * 3;
            float b0 = Mp1[idx], b1 = Mp1[idx + ncb], b2 = Mp1[idx + 2*ncb];
            u32 h1 = ((u32)(b0*nf) ^ (((u32)(b1*nf))*2654435761u)
                                   ^ (((u32)(b2*nf))*805459861u)) & 255u;
            const float* t1 = tl + h1 * 3;
            int pi = d * 33 + w;
            px[pi] = lp(t0[0], t1[0], wp);
            py[pi] = lp(t0[1], t1[1], wp);
            pz[pi] = lp(t0[2], t1[2], wp);
        }
        __syncthreads();

        // pass A: q-upsample each plane row to the 64 output-w positions
        for (int e2 = t; e2 < (nh << 6); e2 += 256) {
            int r = e2 >> 6, d = e2 & 63;
            float fk = (float)d + 0.5f;
            float pq = fminf(fmaxf(fk * iv - 0.5f, 0.f), (float)(nh - 1));
            int q0 = min((int)pq, nh - 2);
            float wq = pq - (float)q0;
            int pi = r * 33 + q0;
            int ub = r * 196 + d;
            uf[ub]       = lp(px[pi], px[pi + 1], wq);
            uf[ub + 64]  = lp(py[pi], py[pi + 1], wq);
            uf[ub + 128] = lp(pz[pi], pz[pi + 1], wq);
        }
        __syncthreads();

        // pass B: r-lerp + store
        float* op = out + (size_t)b * 12582912 + (size_t)(3 * l) * 262144
                        + (size_t)i * 4096;
        #pragma unroll
        for (int it = 0; it < 4; ++it) {
            int pos = it * 256 + t;           // 0..1023
            int j = pos >> 4, d0 = (pos & 15) << 2;
            float fj = (float)j + 0.5f;
            float pr = fminf(fmaxf(fj * iv - 0.5f, 0.f), (float)(nh - 1));
            int r0 = min((int)pr, nh - 2);
            float wr = pr - (float)r0;
            const float* u0 = uf + r0 * 196 + d0;
            const float* u1 = u0 + 196;
            f32x4 ax = *(const f32x4*)(u0);
            f32x4 ay = *(const f32x4*)(u0 + 64);
            f32x4 az = *(const f32x4*)(u0 + 128);
            f32x4 bx = *(const f32x4*)(u1);
            f32x4 by = *(const f32x4*)(u1 + 64);
            f32x4 bz = *(const f32x4*)(u1 + 128);
            int off = j * 64 + d0;
            st4(op + off,          lp(ax.x,bx.x,wr), lp(ax.y,bx.y,wr),
                                   lp(ax.z,bx.z,wr), lp(ax.w,bx.w,wr));
            st4(op + off + 262144, lp(ay.x,by.x,wr), lp(ay.y,by.y,wr),
                                   lp(ay.z,by.z,wr), lp(ay.w,by.w,wr));
            st4(op + off + 524288, lp(az.x,bz.x,wr), lp(az.y,bz.y,wr),
                                   lp(az.z,bz.z,wr), lp(az.w,bz.w,wr));
        }
    } else {
        // ---- identity levels 12..15, j-quarter = l-12 ----
        float4* tab = shb4;                   // [1024]
        float*  xs  = (float*)(shb4 + 1024);  // [3][64][17]
        const int jq = l - 12;

        for (int v = t; v < 1024; v += 256) {
            const float* te = tbl + (size_t)(3072 + v) * 3;   // (12*256+v)*3
            tab[v] = make_float4(te[0], te[1], te[2], 0.f);
        }
        const float* xp = x + (size_t)b * 786432 + (size_t)i * 4096 + jq * 16;
        #pragma unroll
        for (int c = 0; c < 3; ++c)
            for (int k = t; k < 1024; k += 256) {
                int w = k >> 4, jl = k & 15;
                xs[c * 1088 + w * 17 + jl] = xp[(size_t)c * 262144 + w * 64 + jl];
            }
        __syncthreads();

        float nfs[4] = {(float)hp.n[12], (float)hp.n[13],
                        (float)hp.n[14], (float)hp.n[15]};
        float* op = out + (size_t)b * 12582912 + (size_t)36 * 262144
                        + (size_t)i * 4096 + jq * 1024;   // jq*16*64

        int jl = t >> 4, d0 = (t & 15) << 2;
        float xv[3][4];
        #pragma unroll
        for (int dd = 0; dd < 4; ++dd) {
            int wrow = (d0 + dd) * 17 + jl;
            xv[0][dd] = xs[wrow];
            xv[1][dd] = xs[1088 + wrow];
            xv[2][dd] = xs[2176 + wrow];
        }
        #pragma unroll
        for (int u = 0; u < 4; ++u) {
            float4 f[4];
            #pragma unroll
            for (int dd = 0; dd < 4; ++dd) {
                u32 g0 = (u32)(xv[0][dd] * nfs[u]);
                u32 g1 = ((u32)(xv[1][dd] * nfs[u])) * 2654435761u;
                u32 g2 = ((u32)(xv[2][dd] * nfs[u])) * 805459861u;
                f[dd] = tab[(u << 8) | ((g0 ^ g1 ^ g2) & 255u)];
            }
            int off = u * 786432 + jl * 64 + d0;    // u*3*262144
            st4(op + off,          f[0].x, f[1].x, f[2].x, f[3].x);
            st4(op + off + 262144, f[0].y, f[1].y, f[2].y, f[3].y);
            st4(op + off + 524288, f[0].z, f[1].z, f[2].z, f[3].z);
        }
    }
}

// ---------------- host ----------------
extern "C" void kernel_launch(void* const* d_in, const int* in_sizes, int n_in,
                              void* d_out, int out_size, void* d_ws, size_t ws_size,
                              hipStream_t stream)
{
    const float* x   = (const float*)d_in[0];
    const float* tbl = (const float*)d_in[1];
    float* out = (float*)d_out;
    float* ws  = (float*)d_ws;

    // levels computed with the same libm (exp/log/pow) as the Python reference,
    // so the n=63-vs-64 boundary at l=15 matches bit-for-bit.
    HP hp;
    double growth = std::exp(std::log(16.0) / 15.0);
    for (int l = 0; l < 16; ++l)
        hp.n[l] = (int)std::floor(4.0 * std::pow(growth, (double)l));

    hipLaunchKernelGGL(k_pool_base, dim3(2052),    dim3(256), 0, stream, x, ws);
    hipLaunchKernelGGL(k_pyr,       dim3(471),     dim3(256), 0, stream, ws);
    hipLaunchKernelGGL(k_out,       dim3(256, 16), dim3(256), 0, stream, x, ws, tbl, out, hp);
}